// Round 2
// baseline (140.977 us; speedup 1.0000x reference)
//
#include <hip/hip_runtime.h>
#include <hip/hip_bf16.h>

// flex_conv via MFMA:
//   t[k=ic*4+d] per pixel:  t_d = ctr_d*Xs - PX_d (d<3), t_3 = Xs
//   out[o][pixel] = Kmat[o][k] . t[k][pixel]   -> 16x16x32 bf16 MFMA
// Wave = 16 pixels x 32 out-ch, K=64 in two k-chunks.
// Lane l: pixel p=l&15, chunk c=l>>4; computes t for ic in {2c,2c+1,8+2c,8+2c+1}
// giving the B fragment (B[k=c*8+j][n=p]) directly in registers.

#define HH 64
#define WW 512
#define HP 62
#define WP 510
#define IC 16
#define OC 32
#define BS 16

typedef __attribute__((ext_vector_type(8))) short short8;
typedef __attribute__((ext_vector_type(4))) float f32x4;

static __device__ __forceinline__ short f2bf(float f) {
    union { __hip_bfloat16 h; short s; } u;
    u.h = __float2bfloat16(f);
    return u.s;
}

__global__ __launch_bounds__(256) void flex_conv_mfma(
    const float* __restrict__ x,
    const float* __restrict__ kern,
    const float* __restrict__ pts,
    float* __restrict__ out)
{
    const int lane = threadIdx.x & 63;
    const int wave = threadIdx.x >> 6;
    const int strip = blockIdx.x * 4 + wave;   // 0..31, 16 pixels each
    const int i = blockIdx.y;                  // 0..61
    const int b = blockIdx.z;                  // 0..15

    const int p = lane & 15;   // pixel within strip (= n index of MFMA)
    const int c = lane >> 4;   // k-chunk quad

    const int j0 = strip * 16;
    int j = j0 + p;
    const bool active = (j < WP);
    if (!active) j = WP - 1;   // clamp loads for tail lanes

    // ---- A fragments: Kmat[o][k] = kern[o*64 + k]; A[m=p][k = c*8 + t]
    // float4-aligned (p*64*4B + c*8*4B).
    short8 a0lo, a0hi, a1lo, a1hi;
    {
        const float* k0 = kern + (size_t)p * 64 + c * 8;
        const float* k1 = kern + (size_t)(16 + p) * 64 + c * 8;
        const float4* k0v = (const float4*)k0;
        const float4* k1v = (const float4*)k1;
        float4 v0a = k0v[0], v0b = k0v[1], v0c = k0v[8], v0d = k0v[9];
        float4 v1a = k1v[0], v1b = k1v[1], v1c = k1v[8], v1d = k1v[9];
        a0lo[0]=f2bf(v0a.x); a0lo[1]=f2bf(v0a.y); a0lo[2]=f2bf(v0a.z); a0lo[3]=f2bf(v0a.w);
        a0lo[4]=f2bf(v0b.x); a0lo[5]=f2bf(v0b.y); a0lo[6]=f2bf(v0b.z); a0lo[7]=f2bf(v0b.w);
        a0hi[0]=f2bf(v0c.x); a0hi[1]=f2bf(v0c.y); a0hi[2]=f2bf(v0c.z); a0hi[3]=f2bf(v0c.w);
        a0hi[4]=f2bf(v0d.x); a0hi[5]=f2bf(v0d.y); a0hi[6]=f2bf(v0d.z); a0hi[7]=f2bf(v0d.w);
        a1lo[0]=f2bf(v1a.x); a1lo[1]=f2bf(v1a.y); a1lo[2]=f2bf(v1a.z); a1lo[3]=f2bf(v1a.w);
        a1lo[4]=f2bf(v1b.x); a1lo[5]=f2bf(v1b.y); a1lo[6]=f2bf(v1b.z); a1lo[7]=f2bf(v1b.w);
        a1hi[0]=f2bf(v1c.x); a1hi[1]=f2bf(v1c.y); a1hi[2]=f2bf(v1c.z); a1hi[3]=f2bf(v1c.w);
        a1hi[4]=f2bf(v1d.x); a1hi[5]=f2bf(v1d.y); a1hi[6]=f2bf(v1d.z); a1hi[7]=f2bf(v1d.w);
    }

    // ---- pts 3x3 window for this lane's pixel (4 lanes share a pixel; L1 broadcasts)
    float p0[9], p1[9], p2[9];
    const float* pb = pts + (size_t)b * 3 * HH * WW;
    #pragma unroll
    for (int k = 0; k < 3; ++k) {
        #pragma unroll
        for (int f = 0; f < 3; ++f) {
            const size_t off = (size_t)(i + k) * WW + (j + f);
            const int e = k * 3 + f;
            p0[e] = pb[off];
            p1[e] = pb[(size_t)HH * WW + off];
            p2[e] = pb[2 * (size_t)HH * WW + off];
        }
    }
    const float c0 = p0[4], c1 = p1[4], c2 = p2[4];

    // ---- window sums for this lane's 4 input channels -> B fragments
    const float* xb = x + (size_t)b * IC * HH * WW + (size_t)i * WW + j;
    short8 blo, bhi;
    #pragma unroll
    for (int h = 0; h < 2; ++h) {        // h=0: k in [0,32)  h=1: k in [32,64)
        #pragma unroll
        for (int s = 0; s < 2; ++s) {    // two ic per 8-wide k-chunk
            const int ic = h * 8 + 2 * c + s;
            const float* xc = xb + (size_t)ic * HH * WW;
            float xs = 0.f, px0 = 0.f, px1 = 0.f, px2 = 0.f;
            #pragma unroll
            for (int k = 0; k < 3; ++k) {
                #pragma unroll
                for (int f = 0; f < 3; ++f) {
                    const float xv = xc[(size_t)k * WW + f];
                    const int e = k * 3 + f;
                    xs += xv;
                    px0 = fmaf(p0[e], xv, px0);
                    px1 = fmaf(p1[e], xv, px1);
                    px2 = fmaf(p2[e], xv, px2);
                }
            }
            const short t0 = f2bf(fmaf(c0, xs, -px0));
            const short t1 = f2bf(fmaf(c1, xs, -px1));
            const short t2 = f2bf(fmaf(c2, xs, -px2));
            const short t3 = f2bf(xs);
            if (h == 0) { blo[s*4+0]=t0; blo[s*4+1]=t1; blo[s*4+2]=t2; blo[s*4+3]=t3; }
            else        { bhi[s*4+0]=t0; bhi[s*4+1]=t1; bhi[s*4+2]=t2; bhi[s*4+3]=t3; }
        }
    }

    // ---- MFMA: D[m=o][n=pixel]
    f32x4 acc0 = {0.f, 0.f, 0.f, 0.f};
    f32x4 acc1 = {0.f, 0.f, 0.f, 0.f};
    acc0 = __builtin_amdgcn_mfma_f32_16x16x32_bf16(a0lo, blo, acc0, 0, 0, 0);
    acc0 = __builtin_amdgcn_mfma_f32_16x16x32_bf16(a0hi, bhi, acc0, 0, 0, 0);
    acc1 = __builtin_amdgcn_mfma_f32_16x16x32_bf16(a1lo, blo, acc1, 0, 0, 0);
    acc1 = __builtin_amdgcn_mfma_f32_16x16x32_bf16(a1hi, bhi, acc1, 0, 0, 0);

    // ---- epilogue: C/D layout col(n=pixel)=lane&15, row(m=o)=c*4+r
    if (active) {
        float* ob = out + (size_t)b * OC * HP * WP + (size_t)i * WP + j;
        #pragma unroll
        for (int r = 0; r < 4; ++r) {
            const int o = c * 4 + r;
            ob[(size_t)o * HP * WP]        = acc0[r];
            ob[(size_t)(o + 16) * HP * WP] = acc1[r];
        }
    }
}

extern "C" void kernel_launch(void* const* d_in, const int* in_sizes, int n_in,
                              void* d_out, int out_size, void* d_ws, size_t ws_size,
                              hipStream_t stream)
{
    const float* x    = (const float*)d_in[0];
    const float* kern = (const float*)d_in[1];
    const float* pts  = (const float*)d_in[2];
    float* out = (float*)d_out;

    dim3 block(256, 1, 1);
    dim3 grid(8, HP, BS);   // 8 blocks x 4 waves = 32 strips of 16 pixels
    flex_conv_mfma<<<grid, block, 0, stream>>>(x, kern, pts, out);
}

// Round 3
// 122.528 us; speedup vs baseline: 1.1506x; 1.1506x over previous
//
#include <hip/hip_runtime.h>
#include <hip/hip_bf16.h>

// flex_conv via MFMA, vertically-blocked front-end.
// t[k=ic*4+d][pixel]: t_d = ctr_d*Xs - PX_d (d<3), t_3 = Xs
// out[o][pixel] = Kmat[o][k] . t[k][pixel]  -> 16x16x32 bf16 MFMA (layouts
// validated in R2: A[m=p][k=c*8+..], B[k][n=p], D row=c*4+r col=p).
// Wave: 16 pixels wide x RB=2 output rows; lane (p=lane&15, c=lane>>4)
// computes t for ic in {2c,2c+1,8+2c,8+2c+1} -> B fragment in registers.
// Front-end: 4 input rows serve both output rows; 3-tap windows loaded as
// one 4B-aligned float4 per (row,plane) instead of 3 scalars.

#define HH 64
#define WW 512
#define HP 62
#define WP 510
#define IC 16
#define OC 32
#define BS 16
#define RB 2

typedef __attribute__((ext_vector_type(8))) short short8;
typedef __attribute__((ext_vector_type(4))) float f32x4;

// 4-float load with only 4-byte alignment guaranteed.
struct __attribute__((packed, aligned(4))) F4U { float x, y, z, w; };

static __device__ __forceinline__ short f2bf(float f) {
    union { __hip_bfloat16 h; short s; } u;
    u.h = __float2bfloat16(f);
    return u.s;
}

template<bool EDGE>
static __device__ __forceinline__ void run_wave(
    const float* __restrict__ x, const float* __restrict__ kern,
    const float* __restrict__ pts, float* __restrict__ out,
    int b, int i0, int j0, int p, int c)
{
    const int j = j0 + p;
    const int jl = EDGE ? (j > WW - 4 ? WW - 4 : j) : j;
    const bool sh = EDGE && (j > WW - 4);

    // ---- A fragments: Kmat rows o=p and o=16+p, k-chunks c*8 and 32+c*8.
    short8 a0lo, a0hi, a1lo, a1hi;
    {
        const float4* k0v = (const float4*)(kern + (size_t)p * 64 + c * 8);
        const float4* k1v = (const float4*)(kern + (size_t)(16 + p) * 64 + c * 8);
        float4 v0a = k0v[0], v0b = k0v[1], v0c = k0v[8], v0d = k0v[9];
        float4 v1a = k1v[0], v1b = k1v[1], v1c = k1v[8], v1d = k1v[9];
        a0lo[0]=f2bf(v0a.x); a0lo[1]=f2bf(v0a.y); a0lo[2]=f2bf(v0a.z); a0lo[3]=f2bf(v0a.w);
        a0lo[4]=f2bf(v0b.x); a0lo[5]=f2bf(v0b.y); a0lo[6]=f2bf(v0b.z); a0lo[7]=f2bf(v0b.w);
        a0hi[0]=f2bf(v0c.x); a0hi[1]=f2bf(v0c.y); a0hi[2]=f2bf(v0c.z); a0hi[3]=f2bf(v0c.w);
        a0hi[4]=f2bf(v0d.x); a0hi[5]=f2bf(v0d.y); a0hi[6]=f2bf(v0d.z); a0hi[7]=f2bf(v0d.w);
        a1lo[0]=f2bf(v1a.x); a1lo[1]=f2bf(v1a.y); a1lo[2]=f2bf(v1a.z); a1lo[3]=f2bf(v1a.w);
        a1lo[4]=f2bf(v1b.x); a1lo[5]=f2bf(v1b.y); a1lo[6]=f2bf(v1b.z); a1lo[7]=f2bf(v1b.w);
        a1hi[0]=f2bf(v1c.x); a1hi[1]=f2bf(v1c.y); a1hi[2]=f2bf(v1c.z); a1hi[3]=f2bf(v1c.w);
        a1hi[4]=f2bf(v1d.x); a1hi[5]=f2bf(v1d.y); a1hi[6]=f2bf(v1d.z); a1hi[7]=f2bf(v1d.w);
    }

    // ---- per-(ic_local, outrow) window partials
    float xs[4][RB], px0[4][RB], px1[4][RB], px2[4][RB];
    #pragma unroll
    for (int t = 0; t < 4; ++t)
        #pragma unroll
        for (int q = 0; q < RB; ++q) { xs[t][q]=0.f; px0[t][q]=0.f; px1[t][q]=0.f; px2[t][q]=0.f; }
    float c0[RB], c1[RB], c2[RB];

    const float* pbase = pts + (size_t)b * 3 * HH * WW;
    const float* xbase = x + (size_t)b * IC * HH * WW;

    #pragma unroll
    for (int rr = 0; rr < RB + 2; ++rr) {   // input rows i0 .. i0+RB+1 (max 63)
        const size_t roff = (size_t)(i0 + rr) * WW + jl;
        F4U pv0 = *(const F4U*)(pbase + roff);
        F4U pv1 = *(const F4U*)(pbase + (size_t)HH * WW + roff);
        F4U pv2 = *(const F4U*)(pbase + 2 * (size_t)HH * WW + roff);
        const float pa0 = sh ? pv0.y : pv0.x, pm0 = sh ? pv0.z : pv0.y, pz0 = sh ? pv0.w : pv0.z;
        const float pa1 = sh ? pv1.y : pv1.x, pm1 = sh ? pv1.z : pv1.y, pz1 = sh ? pv1.w : pv1.z;
        const float pa2 = sh ? pv2.y : pv2.x, pm2 = sh ? pv2.z : pv2.y, pz2 = sh ? pv2.w : pv2.z;
        if (rr >= 1 && rr <= RB) { c0[rr-1] = pm0; c1[rr-1] = pm1; c2[rr-1] = pm2; }
        #pragma unroll
        for (int t = 0; t < 4; ++t) {
            const int ic = (t >> 1) * 8 + 2 * c + (t & 1);
            F4U xv = *(const F4U*)(xbase + (size_t)ic * HH * WW + roff);
            const float xa = sh ? xv.y : xv.x, xm = sh ? xv.z : xv.y, xz = sh ? xv.w : xv.z;
            const float rsx = xa + xm + xz;
            float r0 = pa0 * xa; r0 = fmaf(pm0, xm, r0); r0 = fmaf(pz0, xz, r0);
            float r1 = pa1 * xa; r1 = fmaf(pm1, xm, r1); r1 = fmaf(pz1, xz, r1);
            float r2 = pa2 * xa; r2 = fmaf(pm2, xm, r2); r2 = fmaf(pz2, xz, r2);
            #pragma unroll
            for (int q = 0; q < RB; ++q) {
                if (rr >= q && rr <= q + 2) {
                    xs[t][q] += rsx; px0[t][q] += r0; px1[t][q] += r1; px2[t][q] += r2;
                }
            }
        }
    }

    // ---- per output row: B fragments -> MFMA -> store
    #pragma unroll
    for (int q = 0; q < RB; ++q) {
        short8 blo, bhi;
        #pragma unroll
        for (int t = 0; t < 4; ++t) {
            const short t0 = f2bf(fmaf(c0[q], xs[t][q], -px0[t][q]));
            const short t1 = f2bf(fmaf(c1[q], xs[t][q], -px1[t][q]));
            const short t2 = f2bf(fmaf(c2[q], xs[t][q], -px2[t][q]));
            const short t3 = f2bf(xs[t][q]);
            const int s = (t & 1) * 4;
            if (t < 2) { blo[s+0]=t0; blo[s+1]=t1; blo[s+2]=t2; blo[s+3]=t3; }
            else       { bhi[s+0]=t0; bhi[s+1]=t1; bhi[s+2]=t2; bhi[s+3]=t3; }
        }
        f32x4 acc0 = {0.f,0.f,0.f,0.f}, acc1 = {0.f,0.f,0.f,0.f};
        acc0 = __builtin_amdgcn_mfma_f32_16x16x32_bf16(a0lo, blo, acc0, 0, 0, 0);
        acc0 = __builtin_amdgcn_mfma_f32_16x16x32_bf16(a0hi, bhi, acc0, 0, 0, 0);
        acc1 = __builtin_amdgcn_mfma_f32_16x16x32_bf16(a1lo, blo, acc1, 0, 0, 0);
        acc1 = __builtin_amdgcn_mfma_f32_16x16x32_bf16(a1hi, bhi, acc1, 0, 0, 0);
        if (j < WP) {
            float* ob = out + (size_t)b * OC * HP * WP + (size_t)(i0 + q) * WP + j;
            #pragma unroll
            for (int r = 0; r < 4; ++r) {
                const int o = c * 4 + r;
                ob[(size_t)o * HP * WP]        = acc0[r];
                ob[(size_t)(o + 16) * HP * WP] = acc1[r];
            }
        }
    }
}

__global__ __launch_bounds__(256) void flex_conv_mfma2(
    const float* __restrict__ x, const float* __restrict__ kern,
    const float* __restrict__ pts, float* __restrict__ out)
{
    const int lane = threadIdx.x & 63;
    const int wave = threadIdx.x >> 6;
    const int strip = blockIdx.x * 4 + wave;   // 0..31
    const int j0 = strip * 16;
    const int i0 = blockIdx.y * RB;            // 0,2,..,60
    const int b  = blockIdx.z;
    const int p = lane & 15;
    const int c = lane >> 4;
    // wave-uniform edge dispatch: only strip 31 (j0=496) can read past col 508
    if (j0 + 15 <= WW - 4) run_wave<false>(x, kern, pts, out, b, i0, j0, p, c);
    else                   run_wave<true >(x, kern, pts, out, b, i0, j0, p, c);
}

extern "C" void kernel_launch(void* const* d_in, const int* in_sizes, int n_in,
                              void* d_out, int out_size, void* d_ws, size_t ws_size,
                              hipStream_t stream)
{
    const float* x    = (const float*)d_in[0];
    const float* kern = (const float*)d_in[1];
    const float* pts  = (const float*)d_in[2];
    float* out = (float*)d_out;

    dim3 block(256, 1, 1);
    dim3 grid(8, HP / RB, BS);   // 8x31x16 blocks, 4 waves each
    flex_conv_mfma2<<<grid, block, 0, stream>>>(x, kern, pts, out);
}

// Round 4
// 113.688 us; speedup vs baseline: 1.2400x; 1.0778x over previous
//
#include <hip/hip_runtime.h>
#include <hip/hip_bf16.h>

// flex_conv via MFMA + cooperative LDS staging.
// t[k=ic*4+d][pixel]: t_d = ctr_d*Xs - PX_d (d<3), t_3 = Xs
// out[o][pixel] = Kmat[o][k] . t[k][pixel]  -> 16x16x32 bf16 MFMA
// (A[m=p][k=c*8+..], B[k][n=p], D row=c*4+r col=p — validated R2/R3).
//
// Block = 256 thr (4 waves) owns a 64-col x RB=4-row output tile.
// Stage 19 planes (16 x + 3 pts) x 6 input rows x 68 cols into LDS with
// coalesced float4 loads, then compute 3x3 windows from LDS.
// Wave w handles tile cols w*16..w*16+15; lane (p=lane&15, c=lane>>4)
// computes t for ic in {2c,2c+1,8+2c,8+2c+1} -> B fragment in registers.

#define HH 64
#define WW 512
#define HP 62
#define WP 510
#define IC 16
#define OC 32
#define BS 16
#define RB 4            // output rows per block
#define TR (RB + 2)     // staged input rows = 6
#define TC 64           // output cols per block
#define LC 68           // LDS row length in floats (need 66)
#define NPL 19          // planes staged: 16 x + 3 pts
#define CPR 17          // float4 chunks per row (17*4 = 68)
#define NROWS (NPL * TR)        // 114
#define NCHUNK (NROWS * CPR)    // 1938

typedef __attribute__((ext_vector_type(8))) short short8;
typedef __attribute__((ext_vector_type(4))) float f32x4;

static __device__ __forceinline__ short f2bf(float f) {
    union { __hip_bfloat16 h; short s; } u;
    u.h = __float2bfloat16(f);
    return u.s;
}

__global__ __launch_bounds__(256) void flex_conv_lds(
    const float* __restrict__ x, const float* __restrict__ kern,
    const float* __restrict__ pts, float* __restrict__ out)
{
    __shared__ float lds[NPL * TR * LC];   // 7752 floats = 31008 B

    const int tid = threadIdx.x;
    const int j0 = blockIdx.x * TC;
    int i0 = blockIdx.y * RB;
    if (i0 > HP - RB) i0 = HP - RB;        // tail overlap (benign identical rewrite)
    const int b = blockIdx.z;

    const float* xb = x + (size_t)b * IC * HH * WW;
    const float* pb = pts + (size_t)b * 3 * HH * WW;

    // ---- cooperative staging: 1938 float4 chunks over 256 threads ----
    #pragma unroll
    for (int rnd = 0; rnd < 8; ++rnd) {
        const int cid = tid + rnd * 256;
        if (cid < NCHUNK) {
            const int row = cid / CPR;           // 0..113 = plane*TR + rr
            const int chunk = cid - row * CPR;   // 0..16
            const int plane = row / TR;          // 0..18
            const int rr = row - plane * TR;     // 0..5
            const float* base = (plane < IC)
                ? (xb + (size_t)plane * HH * WW)
                : (pb + (size_t)(plane - IC) * HH * WW);
            int gcol = j0 + chunk * 4;
            if (gcol > WW - 4) gcol = WW - 4;    // clamp (garbage lands in unused cells)
            const float4 v = *(const float4*)(base + (size_t)(i0 + rr) * WW + gcol);
            *(float4*)(&lds[row * LC + chunk * 4]) = v;
        }
    }
    __syncthreads();

    // ---- A fragments: Kmat rows o=p and o=16+p, k-chunks c*8 and 32+c*8 ----
    const int lane = tid & 63;
    const int wave = tid >> 6;
    const int p = lane & 15;
    const int c = lane >> 4;
    const int tc = wave * 16 + p;        // tile col of this lane's pixel

    short8 a0lo, a0hi, a1lo, a1hi;
    {
        const float4* k0v = (const float4*)(kern + (size_t)p * 64 + c * 8);
        const float4* k1v = (const float4*)(kern + (size_t)(16 + p) * 64 + c * 8);
        float4 v0a = k0v[0], v0b = k0v[1], v0c = k0v[8], v0d = k0v[9];
        float4 v1a = k1v[0], v1b = k1v[1], v1c = k1v[8], v1d = k1v[9];
        a0lo[0]=f2bf(v0a.x); a0lo[1]=f2bf(v0a.y); a0lo[2]=f2bf(v0a.z); a0lo[3]=f2bf(v0a.w);
        a0lo[4]=f2bf(v0b.x); a0lo[5]=f2bf(v0b.y); a0lo[6]=f2bf(v0b.z); a0lo[7]=f2bf(v0b.w);
        a0hi[0]=f2bf(v0c.x); a0hi[1]=f2bf(v0c.y); a0hi[2]=f2bf(v0c.z); a0hi[3]=f2bf(v0c.w);
        a0hi[4]=f2bf(v0d.x); a0hi[5]=f2bf(v0d.y); a0hi[6]=f2bf(v0d.z); a0hi[7]=f2bf(v0d.w);
        a1lo[0]=f2bf(v1a.x); a1lo[1]=f2bf(v1a.y); a1lo[2]=f2bf(v1a.z); a1lo[3]=f2bf(v1a.w);
        a1lo[4]=f2bf(v1b.x); a1lo[5]=f2bf(v1b.y); a1lo[6]=f2bf(v1b.z); a1lo[7]=f2bf(v1b.w);
        a1hi[0]=f2bf(v1c.x); a1hi[1]=f2bf(v1c.y); a1hi[2]=f2bf(v1c.z); a1hi[3]=f2bf(v1c.w);
        a1hi[4]=f2bf(v1d.x); a1hi[5]=f2bf(v1d.y); a1hi[6]=f2bf(v1d.z); a1hi[7]=f2bf(v1d.w);
    }

    // ---- window partials from LDS ----
    float xs[4][RB], px0[4][RB], px1[4][RB], px2[4][RB];
    #pragma unroll
    for (int t = 0; t < 4; ++t)
        #pragma unroll
        for (int q = 0; q < RB; ++q) { xs[t][q]=0.f; px0[t][q]=0.f; px1[t][q]=0.f; px2[t][q]=0.f; }
    float c0[RB], c1[RB], c2[RB];

    #pragma unroll
    for (int rr = 0; rr < TR; ++rr) {
        const float* lp0 = &lds[(IC * TR + rr) * LC + tc];        // pts plane 0
        const float* lp1 = &lds[((IC + 1) * TR + rr) * LC + tc];
        const float* lp2 = &lds[((IC + 2) * TR + rr) * LC + tc];
        const float pa0 = lp0[0], pm0 = lp0[1], pz0 = lp0[2];
        const float pa1 = lp1[0], pm1 = lp1[1], pz1 = lp1[2];
        const float pa2 = lp2[0], pm2 = lp2[1], pz2 = lp2[2];
        if (rr >= 1 && rr <= RB) { c0[rr-1] = pm0; c1[rr-1] = pm1; c2[rr-1] = pm2; }
        #pragma unroll
        for (int t = 0; t < 4; ++t) {
            const int ic = (t >> 1) * 8 + 2 * c + (t & 1);
            const float* lx = &lds[(ic * TR + rr) * LC + tc];
            const float x0 = lx[0], x1 = lx[1], x2 = lx[2];
            const float rsx = x0 + x1 + x2;
            float r0 = pa0 * x0; r0 = fmaf(pm0, x1, r0); r0 = fmaf(pz0, x2, r0);
            float r1 = pa1 * x0; r1 = fmaf(pm1, x1, r1); r1 = fmaf(pz1, x2, r1);
            float r2 = pa2 * x0; r2 = fmaf(pm2, x1, r2); r2 = fmaf(pz2, x2, r2);
            #pragma unroll
            for (int q = 0; q < RB; ++q) {
                if (rr >= q && rr <= q + 2) {
                    xs[t][q] += rsx; px0[t][q] += r0; px1[t][q] += r1; px2[t][q] += r2;
                }
            }
        }
    }

    // ---- per output row: B fragments -> MFMA -> store ----
    const int j = j0 + tc;
    #pragma unroll
    for (int q = 0; q < RB; ++q) {
        short8 blo, bhi;
        #pragma unroll
        for (int t = 0; t < 4; ++t) {
            const short t0 = f2bf(fmaf(c0[q], xs[t][q], -px0[t][q]));
            const short t1 = f2bf(fmaf(c1[q], xs[t][q], -px1[t][q]));
            const short t2 = f2bf(fmaf(c2[q], xs[t][q], -px2[t][q]));
            const short t3 = f2bf(xs[t][q]);
            const int s = (t & 1) * 4;
            if (t < 2) { blo[s+0]=t0; blo[s+1]=t1; blo[s+2]=t2; blo[s+3]=t3; }
            else       { bhi[s+0]=t0; bhi[s+1]=t1; bhi[s+2]=t2; bhi[s+3]=t3; }
        }
        f32x4 acc0 = {0.f,0.f,0.f,0.f}, acc1 = {0.f,0.f,0.f,0.f};
        acc0 = __builtin_amdgcn_mfma_f32_16x16x32_bf16(a0lo, blo, acc0, 0, 0, 0);
        acc0 = __builtin_amdgcn_mfma_f32_16x16x32_bf16(a0hi, bhi, acc0, 0, 0, 0);
        acc1 = __builtin_amdgcn_mfma_f32_16x16x32_bf16(a1lo, blo, acc1, 0, 0, 0);
        acc1 = __builtin_amdgcn_mfma_f32_16x16x32_bf16(a1hi, bhi, acc1, 0, 0, 0);
        if (j < WP) {
            float* ob = out + (size_t)b * OC * HP * WP + (size_t)(i0 + q) * WP + j;
            #pragma unroll
            for (int r = 0; r < 4; ++r) {
                const int o = c * 4 + r;
                ob[(size_t)o * HP * WP]        = acc0[r];
                ob[(size_t)(o + 16) * HP * WP] = acc1[r];
            }
        }
    }
}

extern "C" void kernel_launch(void* const* d_in, const int* in_sizes, int n_in,
                              void* d_out, int out_size, void* d_ws, size_t ws_size,
                              hipStream_t stream)
{
    const float* x    = (const float*)d_in[0];
    const float* kern = (const float*)d_in[1];
    const float* pts  = (const float*)d_in[2];
    float* out = (float*)d_out;

    dim3 block(256, 1, 1);
    dim3 grid(WW / TC, (HP + RB - 1) / RB, BS);   // 8 x 16 x 16 = 2048 blocks
    flex_conv_lds<<<grid, block, 0, stream>>>(x, kern, pts, out);
}